// Round 5
// baseline (4379.491 us; speedup 1.0000x reference)
//
#include <hip/hip_runtime.h>
#include <math.h>

// GRU seq2seq on MI355X. Round 4 (resubmit; infra timeout last round): GRU cell fused
// into GEMM epilogue.
// Gate-fragment weight layout: each 16-col MFMA fragment = one gate x 16 units, so a
// thread's acc[fi][g] are all gates of the SAME (row,unit) -> cell in registers.
// E0: gh0 GEMM (N=1536,K=512) + cell0 (x-side K=4 inline fp32).
// E1: combined [gi1|gh1] GEMM (N=2048,K=1024, A=[h0'|h1]) + cell1.
// D:  ghd GEMM (N=1536,K=512) + decoder cell + FC head (shfl + atomicAdd into out).
// hb ping-pong (U/V) kills the stage-read vs epilogue-write race. fp32 master h state.

#define B_SZ  4096
#define H     512
#define H3    1536
#define TOBS  30
#define TPRED 60

typedef float f32x4 __attribute__((ext_vector_type(4)));
typedef short s16x8 __attribute__((ext_vector_type(8)));
typedef __bf16 bf16x8 __attribute__((ext_vector_type(8)));

__device__ __forceinline__ float b2f(unsigned short u) {
    unsigned v = (unsigned)u << 16; return __builtin_bit_cast(float, v);
}
__device__ __forceinline__ unsigned short f2b(float f) {  // RNE
    unsigned u = __builtin_bit_cast(unsigned, f);
    return (unsigned short)((u + 0x7FFF + ((u >> 16) & 1)) >> 16);
}

typedef __attribute__((address_space(1))) void gvoid;
typedef __attribute__((address_space(3))) void lvoid;
__device__ __forceinline__ void gl16(const void* g, void* l) {
    __builtin_amdgcn_global_load_lds((gvoid*)g, (lvoid*)l, 16, 0, 0);
}

__device__ __forceinline__ f32x4 mfma_bf16(s16x8 a, s16x8 b, f32x4 c) {
    return __builtin_amdgcn_mfma_f32_16x16x32_bf16(
        __builtin_bit_cast(bf16x8, a), __builtin_bit_cast(bf16x8, b), c, 0, 0, 0);
}

__device__ __forceinline__ float sigmoidf_(float v) { return 1.f / (1.f + expf(-v)); }

// Shared GEMM core: tile 128(m) x NJ*32(n), BK=64, 4 waves (2x2), A row-stride 1024.
// XOR chunk swizzle on staging source + LDS reads (both-sides involution, <=2-way).
template<int NJ, int KTOT>
__device__ __forceinline__ void gemm_core(
    const unsigned short* __restrict__ A, const unsigned short* __restrict__ W,
    int m0, int n0, unsigned short* sA, unsigned short* sB, f32x4 (&acc)[4][NJ])
{
    const int tid  = threadIdx.x;
    const int lane = tid & 63;
    const int w    = tid >> 6;
    const int wr = w >> 1, wc = w & 1;
    const int lr = lane & 15;
    const int q  = lane >> 4;
    const int wbase = tid & ~63;

    for (int k0 = 0; k0 < KTOT; k0 += 64) {
#pragma unroll
        for (int s = 0; s < 4; ++s) {
            int i = s * 256 + tid;
            int row = i >> 3, p = i & 7;
            int c = p ^ (row & 7);
            gl16(A + (size_t)(m0 + row) * 1024 + k0 + c * 8, &sA[(s * 256 + wbase) * 8]);
        }
#pragma unroll
        for (int s = 0; s < NJ; ++s) {
            int i = s * 256 + tid;
            int row = i >> 3, p = i & 7;
            int c = p ^ (row & 7);
            gl16(W + (size_t)(n0 + row) * KTOT + k0 + c * 8, &sB[(s * 256 + wbase) * 8]);
        }
        __syncthreads();
#pragma unroll
        for (int kk = 0; kk < 64; kk += 32) {
            int qb = (kk >> 3) + q;
            s16x8 af[4], bf[NJ];
#pragma unroll
            for (int fi = 0; fi < 4; ++fi) {
                int r = wr * 64 + fi * 16 + lr;
                af[fi] = *(const s16x8*)&sA[r * 64 + ((qb ^ (r & 7)) * 8)];
            }
#pragma unroll
            for (int fj = 0; fj < NJ; ++fj) {
                int r = wc * (NJ * 16) + fj * 16 + lr;
                bf[fj] = *(const s16x8*)&sB[r * 64 + ((qb ^ (r & 7)) * 8)];
            }
#pragma unroll
            for (int fi = 0; fi < 4; ++fi)
#pragma unroll
                for (int fj = 0; fj < NJ; ++fj)
                    acc[fi][fj] = mfma_bf16(af[fi], bf[fj], acc[fi][fj]);
        }
        __syncthreads();
    }
}

// E0: gh0 = h0 @ W0'(gate-fragment layout), + layer-0 cell. A = hb_in (h0 half).
__global__ __launch_bounds__(256)
void gemm_e0(const unsigned short* __restrict__ A, const unsigned short* __restrict__ W,
             const float* __restrict__ x, int t,
             const float* __restrict__ Wih, const float* __restrict__ bih,
             const float* __restrict__ bhh,
             float* __restrict__ hf, unsigned short* __restrict__ hbout)
{
    int bid = (int)blockIdx.x;
    int swz = (bid & 7) * 64 + (bid >> 3);
    const int tile_n = swz & 15;
    const int n0 = tile_n * 96;
    const int m0 = (swz >> 4) * 128;

    __shared__ unsigned short sA[128 * 64], sB[96 * 64];
    f32x4 acc[4][3];
#pragma unroll
    for (int i = 0; i < 4; ++i)
#pragma unroll
        for (int j = 0; j < 3; ++j) acc[i][j] = (f32x4){0.f, 0.f, 0.f, 0.f};

    gemm_core<3, 512>(A, W, m0, n0, sA, sB, acc);

    const int lane = threadIdx.x & 63;
    const int w    = threadIdx.x >> 6;
    const int wrw = w >> 1, wcw = w & 1;
    const int lr = lane & 15, q = lane >> 4;
    const int u = tile_n * 32 + wcw * 16 + lr;

    float4 wrv = *(const float4*)(Wih + (size_t)u * 4);
    float4 wzv = *(const float4*)(Wih + (size_t)(512 + u) * 4);
    float4 wnv = *(const float4*)(Wih + (size_t)(1024 + u) * 4);
    float br_ = bih[u], bz_ = bih[512 + u], bn_ = bih[1024 + u];
    float cr_ = bhh[u], cz_ = bhh[512 + u], cn_ = bhh[1024 + u];

#pragma unroll
    for (int fi = 0; fi < 4; ++fi) {
#pragma unroll
        for (int j = 0; j < 4; ++j) {
            int row = m0 + wrw * 64 + fi * 16 + q * 4 + j;
            float4 xv = *(const float4*)(x + (size_t)row * 120 + t * 4);
            float gir = br_ + xv.x * wrv.x + xv.y * wrv.y + xv.z * wrv.z + xv.w * wrv.w;
            float giz = bz_ + xv.x * wzv.x + xv.y * wzv.y + xv.z * wzv.z + xv.w * wzv.w;
            float gin = bn_ + xv.x * wnv.x + xv.y * wnv.y + xv.z * wnv.z + xv.w * wnv.w;
            float rr = sigmoidf_(gir + acc[fi][0][j] + cr_);
            float zz = sigmoidf_(giz + acc[fi][1][j] + cz_);
            float nn = tanhf(gin + rr * (acc[fi][2][j] + cn_));
            size_t hidx = (size_t)row * 512 + u;
            float hn = (1.f - zz) * nn + zz * hf[hidx];
            hf[hidx] = hn;
            hbout[(size_t)row * 1024 + u] = f2b(hn);
        }
    }
}

// E1: combined [gi1|gh1] GEMM over A=[h0'|h1] (K=1024), 4 gates/unit, + layer-1 cell.
__global__ __launch_bounds__(256)
void gemm_e1(const unsigned short* __restrict__ A, const unsigned short* __restrict__ W,
             const float* __restrict__ bih, const float* __restrict__ bhh,
             float* __restrict__ hf, unsigned short* __restrict__ hbout /* +512 applied */)
{
    int bid = (int)blockIdx.x;
    int swz = (bid & 7) * 64 + (bid >> 3);
    const int tile_n = swz & 15;
    const int n0 = tile_n * 128;
    const int m0 = (swz >> 4) * 128;

    __shared__ unsigned short sA[128 * 64], sB[128 * 64];
    f32x4 acc[4][4];
#pragma unroll
    for (int i = 0; i < 4; ++i)
#pragma unroll
        for (int j = 0; j < 4; ++j) acc[i][j] = (f32x4){0.f, 0.f, 0.f, 0.f};

    gemm_core<4, 1024>(A, W, m0, n0, sA, sB, acc);

    const int lane = threadIdx.x & 63;
    const int w    = threadIdx.x >> 6;
    const int wrw = w >> 1, wcw = w & 1;
    const int lr = lane & 15, q = lane >> 4;
    const int u = tile_n * 32 + wcw * 16 + lr;

    float br_ = bih[u] + bhh[u];
    float bz_ = bih[512 + u] + bhh[512 + u];
    float bni = bih[1024 + u], bnh = bhh[1024 + u];

#pragma unroll
    for (int fi = 0; fi < 4; ++fi) {
#pragma unroll
        for (int j = 0; j < 4; ++j) {
            int row = m0 + wrw * 64 + fi * 16 + q * 4 + j;
            float rr = sigmoidf_(acc[fi][0][j] + br_);
            float zz = sigmoidf_(acc[fi][1][j] + bz_);
            float nn = tanhf(acc[fi][2][j] + bni + rr * (acc[fi][3][j] + bnh));
            size_t hidx = (size_t)row * 512 + u;
            float hn = (1.f - zz) * nn + zz * hf[hidx];
            hf[hidx] = hn;
            hbout[(size_t)row * 1024 + u] = f2b(hn);
        }
    }
}

// D: ghd GEMM + decoder cell + FC head (wave shfl-reduce + atomicAdd into out).
__global__ __launch_bounds__(256)
void gemm_d(const unsigned short* __restrict__ A /* hb h1-half */,
            const unsigned short* __restrict__ W,
            const float* __restrict__ dptr, int dstride,
            const float* __restrict__ Wih, const float* __restrict__ bih,
            const float* __restrict__ bhh,
            float* __restrict__ hf, unsigned short* __restrict__ hbout /* +512 applied */,
            const float* __restrict__ Wfc, float* __restrict__ out, int t)
{
    int bid = (int)blockIdx.x;
    int swz = (bid & 7) * 64 + (bid >> 3);
    const int tile_n = swz & 15;
    const int n0 = tile_n * 96;
    const int m0 = (swz >> 4) * 128;

    __shared__ unsigned short sA[128 * 64], sB[96 * 64];
    f32x4 acc[4][3];
#pragma unroll
    for (int i = 0; i < 4; ++i)
#pragma unroll
        for (int j = 0; j < 3; ++j) acc[i][j] = (f32x4){0.f, 0.f, 0.f, 0.f};

    gemm_core<3, 512>(A, W, m0, n0, sA, sB, acc);

    const int lane = threadIdx.x & 63;
    const int w    = threadIdx.x >> 6;
    const int wrw = w >> 1, wcw = w & 1;
    const int lr = lane & 15, q = lane >> 4;
    const int u = tile_n * 32 + wcw * 16 + lr;

    float wr0 = Wih[(size_t)u * 2],            wr1 = Wih[(size_t)u * 2 + 1];
    float wz0 = Wih[(size_t)(512 + u) * 2],    wz1 = Wih[(size_t)(512 + u) * 2 + 1];
    float wn0 = Wih[(size_t)(1024 + u) * 2],   wn1 = Wih[(size_t)(1024 + u) * 2 + 1];
    float br_ = bih[u], bz_ = bih[512 + u], bn_ = bih[1024 + u];
    float cr_ = bhh[u], cz_ = bhh[512 + u], cn_ = bhh[1024 + u];
    float f0 = Wfc[u], f1 = Wfc[512 + u];

#pragma unroll
    for (int fi = 0; fi < 4; ++fi) {
#pragma unroll
        for (int j = 0; j < 4; ++j) {
            int row = m0 + wrw * 64 + fi * 16 + q * 4 + j;
            float x0 = dptr[(size_t)row * dstride + 0];
            float x1 = dptr[(size_t)row * dstride + 1];
            float gir = br_ + x0 * wr0 + x1 * wr1;
            float giz = bz_ + x0 * wz0 + x1 * wz1;
            float gin = bn_ + x0 * wn0 + x1 * wn1;
            float rr = sigmoidf_(gir + acc[fi][0][j] + cr_);
            float zz = sigmoidf_(giz + acc[fi][1][j] + cz_);
            float nn = tanhf(gin + rr * (acc[fi][2][j] + cn_));
            size_t hidx = (size_t)row * 512 + u;
            float hn = (1.f - zz) * nn + zz * hf[hidx];
            hf[hidx] = hn;
            hbout[(size_t)row * 1024 + u] = f2b(hn);

            float p0 = hn * f0, p1 = hn * f1;
#pragma unroll
            for (int m = 1; m < 16; m <<= 1) {
                p0 += __shfl_xor(p0, m);
                p1 += __shfl_xor(p1, m);
            }
            if (lr == 0) {
                atomicAdd(&out[(size_t)row * 120 + t * 2 + 0], p0);
                atomicAdd(&out[(size_t)row * 120 + t * 2 + 1], p1);
            }
        }
    }
}

// Weight preps: gate-fragment layouts.
// W0'/Wd' (1536x512): dst row c: ublock=c/48, g=(c%48)/16, uoff=c%16, u=ublock*16+uoff
__global__ void wprep_rzn(const float* __restrict__ s0, const float* __restrict__ s1,
                          unsigned short* __restrict__ d0, unsigned short* __restrict__ d1)
{
    const float* s = blockIdx.y ? s1 : s0;
    unsigned short* d = blockIdx.y ? d1 : d0;
    int i = blockIdx.x * 256 + threadIdx.x;   // over 1536*512
    int c = i >> 9, k = i & 511;
    int ublock = c / 48, rem = c % 48, g = rem >> 4, uoff = rem & 15;
    int u = ublock * 16 + uoff;
    d[i] = f2b(s[((size_t)(g * 512 + u)) * 512 + k]);
}

// W1' (2048x1024): c: ublock=c>>6, g=(c>>4)&3, uoff=c&15; k<512 -> ih-side, k>=512 -> hh-side
__global__ void wprep_e1(const float* __restrict__ Wih1, const float* __restrict__ Whh1,
                         unsigned short* __restrict__ d)
{
    int i = blockIdx.x * 256 + threadIdx.x;   // over 2048*1024
    int c = i >> 10, k = i & 1023;
    int ublock = c >> 6, g = (c >> 4) & 3, uoff = c & 15;
    int u = ublock * 16 + uoff;
    float v;
    if (g == 0)      v = (k < 512) ? Wih1[(size_t)u * 512 + k]          : Whh1[(size_t)u * 512 + (k - 512)];
    else if (g == 1) v = (k < 512) ? Wih1[(size_t)(512 + u) * 512 + k]  : Whh1[(size_t)(512 + u) * 512 + (k - 512)];
    else if (g == 2) v = (k < 512) ? Wih1[(size_t)(1024 + u) * 512 + k] : 0.f;
    else             v = (k < 512) ? 0.f : Whh1[(size_t)(1024 + u) * 512 + (k - 512)];
    d[i] = f2b(v);
}

__global__ void init_all(const float* __restrict__ x, const float* __restrict__ bfc,
                         float* __restrict__ hf0, float* __restrict__ hf1,
                         unsigned short* __restrict__ hbU, unsigned short* __restrict__ hbV,
                         float* __restrict__ dinbuf, float* __restrict__ out)
{
    int idx = blockIdx.x * 256 + threadIdx.x;  // over B*1024
    if (idx < B_SZ * 512) { hf0[idx] = 0.f; hf1[idx] = 0.f; }
    hbU[idx] = 0; hbV[idx] = 0;
    if (idx < B_SZ * 2)
        dinbuf[idx] = x[(size_t)(idx >> 1) * 120 + 29 * 4 + (idx & 1)];
    if (idx < B_SZ * 120) out[idx] = bfc[idx & 1];
}

extern "C" void kernel_launch(void* const* d_in, const int* in_sizes, int n_in,
                              void* d_out, int out_size, void* d_ws, size_t ws_size,
                              hipStream_t stream)
{
    const float* x    = (const float*)d_in[0];
    const float* Wih0 = (const float*)d_in[1];
    const float* Whh0 = (const float*)d_in[2];
    const float* bih0 = (const float*)d_in[3];
    const float* bhh0 = (const float*)d_in[4];
    const float* Wih1 = (const float*)d_in[5];
    const float* Whh1 = (const float*)d_in[6];
    const float* bih1 = (const float*)d_in[7];
    const float* bhh1 = (const float*)d_in[8];
    const float* Wihd = (const float*)d_in[9];
    const float* Whhd = (const float*)d_in[10];
    const float* bihd = (const float*)d_in[11];
    const float* bhhd = (const float*)d_in[12];
    const float* Wfc  = (const float*)d_in[13];
    const float* bfc  = (const float*)d_in[14];
    float* out = (float*)d_out;

    // ws: hf0,hf1 (B*512 f32) | hbU,hbV (B*1024 u16) | dinbuf | W0' | W1' | Wd'
    char* p = (char*)d_ws;
    float* hf0 = (float*)p;  p += (size_t)B_SZ * 512 * 4;
    float* hf1 = (float*)p;  p += (size_t)B_SZ * 512 * 4;
    unsigned short* hbU = (unsigned short*)p; p += (size_t)B_SZ * 1024 * 2;
    unsigned short* hbV = (unsigned short*)p; p += (size_t)B_SZ * 1024 * 2;
    float* dinbuf = (float*)p; p += (size_t)B_SZ * 2 * 4;
    unsigned short* W0p = (unsigned short*)p; p += (size_t)H3 * 512 * 2;
    unsigned short* W1p = (unsigned short*)p; p += (size_t)2048 * 1024 * 2;
    unsigned short* Wdp = (unsigned short*)p;

    wprep_rzn<<<dim3((H3 * 512) / 256, 2), 256, 0, stream>>>(Whh0, Whhd, W0p, Wdp);
    wprep_e1<<<(2048 * 1024) / 256, 256, 0, stream>>>(Wih1, Whh1, W1p);
    init_all<<<(B_SZ * 1024) / 256, 256, 0, stream>>>(x, bfc, hf0, hf1, hbU, hbV, dinbuf, out);

    unsigned short* hbt[2] = {hbU, hbV};
    for (int t = 0; t < TOBS; ++t) {
        unsigned short* bufR = hbt[t & 1];        // E0 reads (even:U, odd:V)
        unsigned short* bufW = hbt[(t & 1) ^ 1];  // E0 writes opposite; E1 reads it
        // E0: h0' = cell0(h0_old)   [reads bufR.h0, writes bufW.h0]
        gemm_e0<<<512, 256, 0, stream>>>(bufR, W0p, x, t, Wih0, bih0, bhh0, hf0, bufW);
        // E1: h1' = cell1([h0'|h1_old])   [reads bufW full, writes bufR.h1]
        gemm_e1<<<512, 256, 0, stream>>>(bufW, W1p, bih1, bhh1, hf1, bufR + 512);
    }
    // After t=29 (odd): E1 wrote h1_final into V.h1.  D_0 reads V.h1.
    for (int t = 0; t < TPRED; ++t) {
        unsigned short* dR = hbt[(t & 1) ^ 1] + 512;  // even: V.h1, odd: U.h1
        unsigned short* dW = hbt[t & 1] + 512;
        const float* dptr = (t == 0) ? dinbuf : out + (size_t)(t - 1) * 2;
        int dstride = (t == 0) ? 2 : 120;
        gemm_d<<<512, 256, 0, stream>>>(dR, Wdp, dptr, dstride, Wihd, bihd, bhhd,
                                        hf1, dW, Wfc, out, t);
    }
}

// Round 9
// 2499.036 us; speedup vs baseline: 1.7525x; 1.7525x over previous
//
#include <hip/hip_runtime.h>
#include <math.h>

// GRU seq2seq on MI355X. Round 6 source, fourth submission (3x infra failure, no signal):
// decoder FC folded into MFMA (4th gate-fragment [r|z|n|fc] -> pred via 2 intra-wave
// shfls; no atomics, no out-feedback loads) + 2-phase double-buffered K-loop in all
// GEMM cores (stage(next) issued before compute(cur), ONE barrier per K-tile).
// E0: gh0 GEMM (N=1536,K=512,NJ=3) + cell0.  E1: [gi1|gh1] (N=2048,K=1024,NJ=4) + cell1.
// D: [ghd|fc] (N=2048,K=512,NJ=4) + decoder cell; out[t-1] written from fragment 3.
// hb ping-pong (U/V) for stage-read vs epilogue-write races. fp32 master h state.

#define B_SZ  4096
#define H     512
#define H3    1536
#define TOBS  30
#define TPRED 60

typedef float f32x4 __attribute__((ext_vector_type(4)));
typedef short s16x8 __attribute__((ext_vector_type(8)));
typedef __bf16 bf16x8 __attribute__((ext_vector_type(8)));

__device__ __forceinline__ float b2f(unsigned short u) {
    unsigned v = (unsigned)u << 16; return __builtin_bit_cast(float, v);
}
__device__ __forceinline__ unsigned short f2b(float f) {  // RNE
    unsigned u = __builtin_bit_cast(unsigned, f);
    return (unsigned short)((u + 0x7FFF + ((u >> 16) & 1)) >> 16);
}

typedef __attribute__((address_space(1))) void gvoid;
typedef __attribute__((address_space(3))) void lvoid;
__device__ __forceinline__ void gl16(const void* g, void* l) {
    __builtin_amdgcn_global_load_lds((gvoid*)g, (lvoid*)l, 16, 0, 0);
}

__device__ __forceinline__ f32x4 mfma_bf16(s16x8 a, s16x8 b, f32x4 c) {
    return __builtin_amdgcn_mfma_f32_16x16x32_bf16(
        __builtin_bit_cast(bf16x8, a), __builtin_bit_cast(bf16x8, b), c, 0, 0, 0);
}

__device__ __forceinline__ float sigmoidf_(float v) { return 1.f / (1.f + expf(-v)); }

// 2-phase double-buffered GEMM core. Tile 128(m) x NJ*32(n), BK=64, 4 waves (2x2).
// A row-stride 1024 (hb layout), W row-stride KTOT. XOR chunk swizzle both sides.
// One __syncthreads per K-tile; stage(next) issued before compute(cur).
template<int NJ, int KTOT>
__device__ __forceinline__ void gemm_core2(
    const unsigned short* __restrict__ A, const unsigned short* __restrict__ W,
    int m0, int n0,
    unsigned short* __restrict__ sA, unsigned short* __restrict__ sB,  // 2 buffers each
    f32x4 (&acc)[4][NJ])
{
    const int tid  = threadIdx.x;
    const int lane = tid & 63;
    const int w    = tid >> 6;
    const int wr = w >> 1, wc = w & 1;
    const int lr = lane & 15;
    const int q  = lane >> 4;
    const int wbase = tid & ~63;
    const int NT = KTOT / 64;
    const int ASZ = 128 * 64, BSZ = NJ * 32 * 64;

    auto stage = [&](int buf, int k0) {
        unsigned short* dA = sA + buf * ASZ;
        unsigned short* dB = sB + buf * BSZ;
#pragma unroll
        for (int s = 0; s < 4; ++s) {
            int i = s * 256 + tid;
            int row = i >> 3, p = i & 7;
            int c = p ^ (row & 7);
            gl16(A + (size_t)(m0 + row) * 1024 + k0 + c * 8, dA + (s * 256 + wbase) * 8);
        }
#pragma unroll
        for (int s = 0; s < NJ; ++s) {
            int i = s * 256 + tid;
            int row = i >> 3, p = i & 7;
            int c = p ^ (row & 7);
            gl16(W + (size_t)(n0 + row) * KTOT + k0 + c * 8, dB + (s * 256 + wbase) * 8);
        }
    };

    stage(0, 0);
    __syncthreads();
#pragma unroll
    for (int ti = 0; ti < NT; ++ti) {
        const int cur = ti & 1;
        if (ti + 1 < NT) stage(cur ^ 1, (ti + 1) * 64);
        const unsigned short* cA = sA + cur * ASZ;
        const unsigned short* cB = sB + cur * BSZ;
#pragma unroll
        for (int kk = 0; kk < 64; kk += 32) {
            int qb = (kk >> 3) + q;
            s16x8 af[4], bf[NJ];
#pragma unroll
            for (int fi = 0; fi < 4; ++fi) {
                int r = wr * 64 + fi * 16 + lr;
                af[fi] = *(const s16x8*)&cA[r * 64 + ((qb ^ (r & 7)) * 8)];
            }
#pragma unroll
            for (int fj = 0; fj < NJ; ++fj) {
                int r = wc * (NJ * 16) + fj * 16 + lr;
                bf[fj] = *(const s16x8*)&cB[r * 64 + ((qb ^ (r & 7)) * 8)];
            }
#pragma unroll
            for (int fi = 0; fi < 4; ++fi)
#pragma unroll
                for (int fj = 0; fj < NJ; ++fj)
                    acc[fi][fj] = mfma_bf16(af[fi], bf[fj], acc[fi][fj]);
        }
        __syncthreads();  // drains this iter's stage (vmcnt) + guards buffer reuse
    }
}

// E0: gh0 GEMM (NJ=3) + layer-0 cell (x-side K=4 inline fp32).
__global__ __launch_bounds__(256)
void gemm_e0(const unsigned short* __restrict__ A, const unsigned short* __restrict__ W,
             const float* __restrict__ x, int t,
             const float* __restrict__ Wih, const float* __restrict__ bih,
             const float* __restrict__ bhh,
             float* __restrict__ hf, unsigned short* __restrict__ hbout)
{
    int bid = (int)blockIdx.x;
    int swz = (bid & 7) * 64 + (bid >> 3);
    const int tile_n = swz & 15;
    const int n0 = tile_n * 96;
    const int m0 = (swz >> 4) * 128;

    __shared__ unsigned short sA[2 * 128 * 64], sB[2 * 96 * 64];
    f32x4 acc[4][3];
#pragma unroll
    for (int i = 0; i < 4; ++i)
#pragma unroll
        for (int j = 0; j < 3; ++j) acc[i][j] = (f32x4){0.f, 0.f, 0.f, 0.f};

    gemm_core2<3, 512>(A, W, m0, n0, sA, sB, acc);

    const int lane = threadIdx.x & 63;
    const int w    = threadIdx.x >> 6;
    const int wrw = w >> 1, wcw = w & 1;
    const int lr = lane & 15, q = lane >> 4;
    const int u = tile_n * 32 + wcw * 16 + lr;

    float4 wrv = *(const float4*)(Wih + (size_t)u * 4);
    float4 wzv = *(const float4*)(Wih + (size_t)(512 + u) * 4);
    float4 wnv = *(const float4*)(Wih + (size_t)(1024 + u) * 4);
    float br_ = bih[u], bz_ = bih[512 + u], bn_ = bih[1024 + u];
    float cr_ = bhh[u], cz_ = bhh[512 + u], cn_ = bhh[1024 + u];

#pragma unroll
    for (int fi = 0; fi < 4; ++fi) {
#pragma unroll
        for (int j = 0; j < 4; ++j) {
            int row = m0 + wrw * 64 + fi * 16 + q * 4 + j;
            float4 xv = *(const float4*)(x + (size_t)row * 120 + t * 4);
            float gir = br_ + xv.x * wrv.x + xv.y * wrv.y + xv.z * wrv.z + xv.w * wrv.w;
            float giz = bz_ + xv.x * wzv.x + xv.y * wzv.y + xv.z * wzv.z + xv.w * wzv.w;
            float gin = bn_ + xv.x * wnv.x + xv.y * wnv.y + xv.z * wnv.z + xv.w * wnv.w;
            float rr = sigmoidf_(gir + acc[fi][0][j] + cr_);
            float zz = sigmoidf_(giz + acc[fi][1][j] + cz_);
            float nn = tanhf(gin + rr * (acc[fi][2][j] + cn_));
            size_t hidx = (size_t)row * 512 + u;
            float hn = (1.f - zz) * nn + zz * hf[hidx];
            hf[hidx] = hn;
            hbout[(size_t)row * 1024 + u] = f2b(hn);
        }
    }
}

// E1: combined [gi1|gh1] GEMM (NJ=4, K=1024) + layer-1 cell.
__global__ __launch_bounds__(256)
void gemm_e1(const unsigned short* __restrict__ A, const unsigned short* __restrict__ W,
             const float* __restrict__ bih, const float* __restrict__ bhh,
             float* __restrict__ hf, unsigned short* __restrict__ hbout /* +512 applied */)
{
    int bid = (int)blockIdx.x;
    int swz = (bid & 7) * 64 + (bid >> 3);
    const int tile_n = swz & 15;
    const int n0 = tile_n * 128;
    const int m0 = (swz >> 4) * 128;

    __shared__ unsigned short sA[2 * 128 * 64], sB[2 * 128 * 64];
    f32x4 acc[4][4];
#pragma unroll
    for (int i = 0; i < 4; ++i)
#pragma unroll
        for (int j = 0; j < 4; ++j) acc[i][j] = (f32x4){0.f, 0.f, 0.f, 0.f};

    gemm_core2<4, 1024>(A, W, m0, n0, sA, sB, acc);

    const int lane = threadIdx.x & 63;
    const int w    = threadIdx.x >> 6;
    const int wrw = w >> 1, wcw = w & 1;
    const int lr = lane & 15, q = lane >> 4;
    const int u = tile_n * 32 + wcw * 16 + lr;

    float br_ = bih[u] + bhh[u];
    float bz_ = bih[512 + u] + bhh[512 + u];
    float bni = bih[1024 + u], bnh = bhh[1024 + u];

#pragma unroll
    for (int fi = 0; fi < 4; ++fi) {
#pragma unroll
        for (int j = 0; j < 4; ++j) {
            int row = m0 + wrw * 64 + fi * 16 + q * 4 + j;
            float rr = sigmoidf_(acc[fi][0][j] + br_);
            float zz = sigmoidf_(acc[fi][1][j] + bz_);
            float nn = tanhf(acc[fi][2][j] + bni + rr * (acc[fi][3][j] + bnh));
            size_t hidx = (size_t)row * 512 + u;
            float hn = (1.f - zz) * nn + zz * hf[hidx];
            hf[hidx] = hn;
            hbout[(size_t)row * 1024 + u] = f2b(hn);
        }
    }
}

// D: [ghd|fc] GEMM (NJ=4, K=512) + decoder cell. Fragment 3 = FC output:
// pred_{t-1} = acc[fi][3] cols 0,1 (Wfc rows embedded in W'); grabbed via 2 shfls.
// out[:, t-1] written by tile_n==0/wcw==0/lr==0 threads (plain stores, no atomics).
__global__ __launch_bounds__(256)
void gemm_d(const unsigned short* __restrict__ A /* hb h1-half */,
            const unsigned short* __restrict__ W,
            const float* __restrict__ dinbuf, int t,
            const float* __restrict__ Wih, const float* __restrict__ bih,
            const float* __restrict__ bhh, const float* __restrict__ bfc,
            float* __restrict__ hf, unsigned short* __restrict__ hbout /* +512 applied */,
            float* __restrict__ out)
{
    int bid = (int)blockIdx.x;
    int swz = (bid & 7) * 64 + (bid >> 3);
    const int tile_n = swz & 15;
    const int n0 = tile_n * 128;
    const int m0 = (swz >> 4) * 128;

    __shared__ unsigned short sA[2 * 128 * 64], sB[2 * 128 * 64];
    f32x4 acc[4][4];
#pragma unroll
    for (int i = 0; i < 4; ++i)
#pragma unroll
        for (int j = 0; j < 4; ++j) acc[i][j] = (f32x4){0.f, 0.f, 0.f, 0.f};

    gemm_core2<4, 512>(A, W, m0, n0, sA, sB, acc);

    const int lane = threadIdx.x & 63;
    const int w    = threadIdx.x >> 6;
    const int wrw = w >> 1, wcw = w & 1;
    const int lr = lane & 15, q = lane >> 4;
    const int u = tile_n * 32 + wcw * 16 + lr;

    float wr0 = Wih[(size_t)u * 2],          wr1 = Wih[(size_t)u * 2 + 1];
    float wz0 = Wih[(size_t)(512 + u) * 2],  wz1 = Wih[(size_t)(512 + u) * 2 + 1];
    float wn0 = Wih[(size_t)(1024 + u) * 2], wn1 = Wih[(size_t)(1024 + u) * 2 + 1];
    float br_ = bih[u], bz_ = bih[512 + u], bn_ = bih[1024 + u];
    float cr_ = bhh[u], cz_ = bhh[512 + u], cn_ = bhh[1024 + u];
    float bfc0 = bfc[0], bfc1 = bfc[1];
    const bool wout = (tile_n == 0) && (wcw == 0) && (lr == 0);

#pragma unroll
    for (int fi = 0; fi < 4; ++fi) {
#pragma unroll
        for (int j = 0; j < 4; ++j) {
            int row = m0 + wrw * 64 + fi * 16 + q * 4 + j;
            // pred_{t-1} from fragment 3, cols 0/1 of this q-group
            float p0 = __shfl(acc[fi][3][j], (lane & 48) | 0) + bfc0;
            float p1 = __shfl(acc[fi][3][j], (lane & 48) | 1) + bfc1;
            float x0, x1;
            if (t == 0) { x0 = dinbuf[row * 2]; x1 = dinbuf[row * 2 + 1]; }
            else        { x0 = p0; x1 = p1; }
            float gir = br_ + x0 * wr0 + x1 * wr1;
            float giz = bz_ + x0 * wz0 + x1 * wz1;
            float gin = bn_ + x0 * wn0 + x1 * wn1;
            float rr = sigmoidf_(gir + acc[fi][0][j] + cr_);
            float zz = sigmoidf_(giz + acc[fi][1][j] + cz_);
            float nn = tanhf(gin + rr * (acc[fi][2][j] + cn_));
            size_t hidx = (size_t)row * 512 + u;
            float hn = (1.f - zz) * nn + zz * hf[hidx];
            hf[hidx] = hn;
            hbout[(size_t)row * 1024 + u] = f2b(hn);
            if (t > 0 && wout) {
                out[(size_t)row * 120 + (t - 1) * 2 + 0] = p0;
                out[(size_t)row * 120 + (t - 1) * 2 + 1] = p1;
            }
        }
    }
}

// Final pred_59 = Wfc @ h_60 + bfc. One 64-lane wave per batch row.
__global__ __launch_bounds__(64)
void fc_last(const unsigned short* __restrict__ hb /* h1-half, +512 applied */,
             const float* __restrict__ Wfc, const float* __restrict__ bfc,
             float* __restrict__ out)
{
    int row = blockIdx.x, lane = threadIdx.x;
    const unsigned short* hrow = hb + (size_t)row * 1024;
    float a0 = 0.f, a1 = 0.f;
#pragma unroll
    for (int kb = 0; kb < 8; ++kb) {
        int k = kb * 64 + lane;
        float hv = b2f(hrow[k]);
        a0 += hv * Wfc[k];
        a1 += hv * Wfc[512 + k];
    }
#pragma unroll
    for (int m = 32; m; m >>= 1) { a0 += __shfl_xor(a0, m); a1 += __shfl_xor(a1, m); }
    if (lane == 0) {
        out[(size_t)row * 120 + 118] = a0 + bfc[0];
        out[(size_t)row * 120 + 119] = a1 + bfc[1];
    }
}

// W0' (1536x512) for E0: row c: ublock=c/48, g=(c%48)/16, u=ublock*16+(c%16)
__global__ void wprep_rzn(const float* __restrict__ s, unsigned short* __restrict__ d)
{
    int i = blockIdx.x * 256 + threadIdx.x;   // over 1536*512
    int c = i >> 9, k = i & 511;
    int ublock = c / 48, rem = c % 48, g = rem >> 4, uoff = rem & 15;
    int u = ublock * 16 + uoff;
    d[i] = f2b(s[((size_t)(g * 512 + u)) * 512 + k]);
}

// W1' (2048x1024) for E1: c: ublock=c>>6, g=(c>>4)&3, uoff=c&15; k<512 ih / k>=512 hh
__global__ void wprep_e1(const float* __restrict__ Wih1, const float* __restrict__ Whh1,
                         unsigned short* __restrict__ d)
{
    int i = blockIdx.x * 256 + threadIdx.x;   // over 2048*1024
    int c = i >> 10, k = i & 1023;
    int ublock = c >> 6, g = (c >> 4) & 3, uoff = c & 15;
    int u = ublock * 16 + uoff;
    float v;
    if (g == 0)      v = (k < 512) ? Wih1[(size_t)u * 512 + k]          : Whh1[(size_t)u * 512 + (k - 512)];
    else if (g == 1) v = (k < 512) ? Wih1[(size_t)(512 + u) * 512 + k]  : Whh1[(size_t)(512 + u) * 512 + (k - 512)];
    else if (g == 2) v = (k < 512) ? Wih1[(size_t)(1024 + u) * 512 + k] : 0.f;
    else             v = (k < 512) ? 0.f : Whh1[(size_t)(1024 + u) * 512 + (k - 512)];
    d[i] = f2b(v);
}

// Wd' (2048x512) for D: c: ublock=c>>6, g=(c>>4)&3, uoff=c&15.
// g<3: Whhd gate rows; g==3: uoff<2 -> Wfc row uoff, else 0.
__global__ void wprep_d(const float* __restrict__ Whhd, const float* __restrict__ Wfc,
                        unsigned short* __restrict__ d)
{
    int i = blockIdx.x * 256 + threadIdx.x;   // over 2048*512
    int c = i >> 9, k = i & 511;
    int ublock = c >> 6, g = (c >> 4) & 3, uoff = c & 15;
    int u = ublock * 16 + uoff;
    float v;
    if (g < 3)           v = Whhd[((size_t)(g * 512 + u)) * 512 + k];
    else if (uoff < 2)   v = Wfc[(size_t)uoff * 512 + k];
    else                 v = 0.f;
    d[i] = f2b(v);
}

__global__ void init_all(const float* __restrict__ x,
                         float* __restrict__ hf0, float* __restrict__ hf1,
                         unsigned short* __restrict__ hbU, unsigned short* __restrict__ hbV,
                         float* __restrict__ dinbuf)
{
    int idx = blockIdx.x * 256 + threadIdx.x;  // over B*1024
    if (idx < B_SZ * 512) { hf0[idx] = 0.f; hf1[idx] = 0.f; }
    hbU[idx] = 0; hbV[idx] = 0;
    if (idx < B_SZ * 2)
        dinbuf[idx] = x[(size_t)(idx >> 1) * 120 + 29 * 4 + (idx & 1)];
}

extern "C" void kernel_launch(void* const* d_in, const int* in_sizes, int n_in,
                              void* d_out, int out_size, void* d_ws, size_t ws_size,
                              hipStream_t stream)
{
    const float* x    = (const float*)d_in[0];
    const float* Wih0 = (const float*)d_in[1];
    const float* Whh0 = (const float*)d_in[2];
    const float* bih0 = (const float*)d_in[3];
    const float* bhh0 = (const float*)d_in[4];
    const float* Wih1 = (const float*)d_in[5];
    const float* Whh1 = (const float*)d_in[6];
    const float* bih1 = (const float*)d_in[7];
    const float* bhh1 = (const float*)d_in[8];
    const float* Wihd = (const float*)d_in[9];
    const float* Whhd = (const float*)d_in[10];
    const float* bihd = (const float*)d_in[11];
    const float* bhhd = (const float*)d_in[12];
    const float* Wfc  = (const float*)d_in[13];
    const float* bfc  = (const float*)d_in[14];
    float* out = (float*)d_out;

    // ws: hf0,hf1 (B*512 f32) | hbU,hbV (B*1024 u16) | dinbuf | W0' | W1' | Wd'
    char* p = (char*)d_ws;
    float* hf0 = (float*)p;  p += (size_t)B_SZ * 512 * 4;
    float* hf1 = (float*)p;  p += (size_t)B_SZ * 512 * 4;
    unsigned short* hbU = (unsigned short*)p; p += (size_t)B_SZ * 1024 * 2;
    unsigned short* hbV = (unsigned short*)p; p += (size_t)B_SZ * 1024 * 2;
    float* dinbuf = (float*)p; p += (size_t)B_SZ * 2 * 4;
    unsigned short* W0p = (unsigned short*)p; p += (size_t)1536 * 512 * 2;
    unsigned short* W1p = (unsigned short*)p; p += (size_t)2048 * 1024 * 2;
    unsigned short* Wdp = (unsigned short*)p;

    wprep_rzn<<<(1536 * 512) / 256, 256, 0, stream>>>(Whh0, W0p);
    wprep_e1<<<(2048 * 1024) / 256, 256, 0, stream>>>(Wih1, Whh1, W1p);
    wprep_d<<<(2048 * 512) / 256, 256, 0, stream>>>(Whhd, Wfc, Wdp);
    init_all<<<(B_SZ * 1024) / 256, 256, 0, stream>>>(x, hf0, hf1, hbU, hbV, dinbuf);

    unsigned short* hbt[2] = {hbU, hbV};
    for (int t = 0; t < TOBS; ++t) {
        unsigned short* bufR = hbt[t & 1];        // E0 reads
        unsigned short* bufW = hbt[(t & 1) ^ 1];  // E0 writes; E1 reads
        gemm_e0<<<512, 256, 0, stream>>>(bufR, W0p, x, t, Wih0, bih0, bhh0, hf0, bufW);
        gemm_e1<<<512, 256, 0, stream>>>(bufW, W1p, bih1, bhh1, hf1, bufR + 512);
    }
    // After t=29 (odd): h1_final in V.h1. Decoder ping-pongs from there.
    for (int t = 0; t < TPRED; ++t) {
        unsigned short* dR = hbt[(t & 1) ^ 1] + 512;  // A = h_t
        unsigned short* dW = hbt[t & 1] + 512;        // h_{t+1}
        gemm_d<<<512, 256, 0, stream>>>(dR, Wdp, dinbuf, t, Wihd, bihd, bhhd, bfc,
                                        hf1, dW, out);
    }
    // pred_59 = FC(h_60); h_60 written by t=59 into hbt[1]+512 (V.h1)
    fc_last<<<B_SZ, 64, 0, stream>>>(hbt[1] + 512, Wfc, bfc, out);
}

// Round 10
// 2429.710 us; speedup vs baseline: 1.8025x; 1.0285x over previous
//
#include <hip/hip_runtime.h>
#include <math.h>

// GRU seq2seq on MI355X. Round 9: (1) E1 zero-padding removed via split n-accumulator
// (NJ=3, K=1024, n-fragment accumulates into acc_ni for K-tiles<8, acc_nh for >=8:
// 17.2->12.9 GF, -25% MFMA); (2) paired launches {E1_t || E0_{t+1}} (independent chains)
// -> encoder 60->31 launches; (3) separate ping-pong h buffers (h0a/b, h1a/b, stride 512).
// D kernel unchanged (NJ=4 with fc fragment -> pred via shfl, no atomics).
// 2-phase double-buffered GEMM core everywhere. fp32 master h state.

#define B_SZ  4096
#define H     512
#define TOBS  30
#define TPRED 60

typedef float f32x4 __attribute__((ext_vector_type(4)));
typedef short s16x8 __attribute__((ext_vector_type(8)));
typedef __bf16 bf16x8 __attribute__((ext_vector_type(8)));

__device__ __forceinline__ float b2f(unsigned short u) {
    unsigned v = (unsigned)u << 16; return __builtin_bit_cast(float, v);
}
__device__ __forceinline__ unsigned short f2b(float f) {  // RNE
    unsigned u = __builtin_bit_cast(unsigned, f);
    return (unsigned short)((u + 0x7FFF + ((u >> 16) & 1)) >> 16);
}

typedef __attribute__((address_space(1))) void gvoid;
typedef __attribute__((address_space(3))) void lvoid;
__device__ __forceinline__ void gl16(const void* g, void* l) {
    __builtin_amdgcn_global_load_lds((gvoid*)g, (lvoid*)l, 16, 0, 0);
}

__device__ __forceinline__ f32x4 mfma_bf16(s16x8 a, s16x8 b, f32x4 c) {
    return __builtin_amdgcn_mfma_f32_16x16x32_bf16(
        __builtin_bit_cast(bf16x8, a), __builtin_bit_cast(bf16x8, b), c, 0, 0, 0);
}

__device__ __forceinline__ float sigmoidf_(float v) { return 1.f / (1.f + expf(-v)); }

// 2-phase double-buffered GEMM core. Tile 128(m) x NJ*32(n), BK=64, 4 waves (2x2).
// A row-stride 512; K-tiles < 512 read A0, >= 512 read A1 (E1's [h0|h1] concat).
// If SPLIT: last fragment (fj==NJ-1) accumulates into acc[][NJ] for ti >= NT/2.
// XOR chunk swizzle both sides. One __syncthreads per K-tile.
template<int NJ, int KTOT, int SPLIT>
__device__ __forceinline__ void gemm_core2(
    const unsigned short* __restrict__ A0, const unsigned short* __restrict__ A1,
    const unsigned short* __restrict__ W,
    int m0, int n0,
    unsigned short* __restrict__ sA, unsigned short* __restrict__ sB,
    f32x4 (&acc)[4][NJ + SPLIT])
{
    const int tid  = threadIdx.x;
    const int lane = tid & 63;
    const int w    = tid >> 6;
    const int wr = w >> 1, wc = w & 1;
    const int lr = lane & 15;
    const int q  = lane >> 4;
    const int wbase = tid & ~63;
    const int NT = KTOT / 64;
    const int ASZ = 128 * 64, BSZ = NJ * 32 * 64;

    auto stage = [&](int buf, int k0) {
        unsigned short* dA = sA + buf * ASZ;
        unsigned short* dB = sB + buf * BSZ;
        const unsigned short* Ab = (SPLIT && k0 >= 512) ? A1 : A0;
        const int ak0 = (SPLIT && k0 >= 512) ? k0 - 512 : k0;
#pragma unroll
        for (int s = 0; s < 4; ++s) {
            int i = s * 256 + tid;
            int row = i >> 3, p = i & 7;
            int c = p ^ (row & 7);
            gl16(Ab + (size_t)(m0 + row) * 512 + ak0 + c * 8, dA + (s * 256 + wbase) * 8);
        }
#pragma unroll
        for (int s = 0; s < NJ; ++s) {
            int i = s * 256 + tid;
            int row = i >> 3, p = i & 7;
            int c = p ^ (row & 7);
            gl16(W + (size_t)(n0 + row) * KTOT + k0 + c * 8, dB + (s * 256 + wbase) * 8);
        }
    };

    stage(0, 0);
    __syncthreads();
#pragma unroll
    for (int ti = 0; ti < NT; ++ti) {
        const int cur = ti & 1;
        if (ti + 1 < NT) stage(cur ^ 1, (ti + 1) * 64);
        const unsigned short* cA = sA + cur * ASZ;
        const unsigned short* cB = sB + cur * BSZ;
#pragma unroll
        for (int kk = 0; kk < 64; kk += 32) {
            int qb = (kk >> 3) + q;
            s16x8 af[4], bf[NJ];
#pragma unroll
            for (int fi = 0; fi < 4; ++fi) {
                int r = wr * 64 + fi * 16 + lr;
                af[fi] = *(const s16x8*)&cA[r * 64 + ((qb ^ (r & 7)) * 8)];
            }
#pragma unroll
            for (int fj = 0; fj < NJ; ++fj) {
                int r = wc * (NJ * 16) + fj * 16 + lr;
                bf[fj] = *(const s16x8*)&cB[r * 64 + ((qb ^ (r & 7)) * 8)];
            }
#pragma unroll
            for (int fi = 0; fi < 4; ++fi)
#pragma unroll
                for (int fj = 0; fj < NJ; ++fj) {
                    const int dst = (SPLIT && fj == NJ - 1 && ti >= NT / 2) ? NJ : fj;
                    acc[fi][dst] = mfma_bf16(af[fi], bf[fj], acc[fi][dst]);
                }
        }
        __syncthreads();
    }
}

// Paired encoder kernel. roles: 1=E1 only, 2=E0 only, 3=both (grid 1024, bid<512 -> E1).
// E1: [gi1|gh1] GEMM NJ=3, K=1024 (A = [h0_{t+1} | h1_t]), split n-acc, + cell1.
// E0: gh0 GEMM NJ=3, K=512, + cell0 (x-side K=4 inline fp32).
__global__ __launch_bounds__(256)
void gemm_enc(const unsigned short* __restrict__ e1_h0, const unsigned short* __restrict__ e1_h1in,
              unsigned short* __restrict__ e1_h1out, const unsigned short* __restrict__ W1,
              const float* __restrict__ bih1, const float* __restrict__ bhh1,
              float* __restrict__ hf1,
              const unsigned short* __restrict__ e0_h0in, unsigned short* __restrict__ e0_h0out,
              const unsigned short* __restrict__ W0,
              const float* __restrict__ x, int t,
              const float* __restrict__ Wih0, const float* __restrict__ bih0,
              const float* __restrict__ bhh0, float* __restrict__ hf0,
              int roles)
{
    __shared__ unsigned short sA[2 * 128 * 64], sB[2 * 96 * 64];

    int bid = (int)blockIdx.x;
    bool isE1;
    if (roles == 3) { isE1 = bid < 512; bid &= 511; }
    else            { isE1 = (roles == 1); }

    int swz = (bid & 7) * 64 + (bid >> 3);
    const int tile_n = swz & 15;
    const int n0 = tile_n * 96;
    const int m0 = (swz >> 4) * 128;

    const int lane = threadIdx.x & 63;
    const int w    = threadIdx.x >> 6;
    const int wrw = w >> 1, wcw = w & 1;
    const int lr = lane & 15, q = lane >> 4;
    const int u = tile_n * 32 + wcw * 16 + lr;

    if (isE1) {
        f32x4 acc[4][4];
#pragma unroll
        for (int i = 0; i < 4; ++i)
#pragma unroll
            for (int j = 0; j < 4; ++j) acc[i][j] = (f32x4){0.f, 0.f, 0.f, 0.f};

        gemm_core2<3, 1024, 1>(e1_h0, e1_h1in, W1, m0, n0, sA, sB, acc);

        float br_ = bih1[u] + bhh1[u];
        float bz_ = bih1[512 + u] + bhh1[512 + u];
        float bni = bih1[1024 + u], bnh = bhh1[1024 + u];
#pragma unroll
        for (int fi = 0; fi < 4; ++fi) {
#pragma unroll
            for (int j = 0; j < 4; ++j) {
                int row = m0 + wrw * 64 + fi * 16 + q * 4 + j;
                float rr = sigmoidf_(acc[fi][0][j] + br_);
                float zz = sigmoidf_(acc[fi][1][j] + bz_);
                float nn = tanhf(acc[fi][2][j] + bni + rr * (acc[fi][3][j] + bnh));
                size_t hidx = (size_t)row * 512 + u;
                float hn = (1.f - zz) * nn + zz * hf1[hidx];
                hf1[hidx] = hn;
                e1_h1out[hidx] = f2b(hn);
            }
        }
    } else {
        f32x4 acc[4][3];
#pragma unroll
        for (int i = 0; i < 4; ++i)
#pragma unroll
            for (int j = 0; j < 3; ++j) acc[i][j] = (f32x4){0.f, 0.f, 0.f, 0.f};

        gemm_core2<3, 512, 0>(e0_h0in, e0_h0in, W0, m0, n0, sA, sB, acc);

        float4 wrv = *(const float4*)(Wih0 + (size_t)u * 4);
        float4 wzv = *(const float4*)(Wih0 + (size_t)(512 + u) * 4);
        float4 wnv = *(const float4*)(Wih0 + (size_t)(1024 + u) * 4);
        float br_ = bih0[u], bz_ = bih0[512 + u], bn_ = bih0[1024 + u];
        float cr_ = bhh0[u], cz_ = bhh0[512 + u], cn_ = bhh0[1024 + u];
#pragma unroll
        for (int fi = 0; fi < 4; ++fi) {
#pragma unroll
            for (int j = 0; j < 4; ++j) {
                int row = m0 + wrw * 64 + fi * 16 + q * 4 + j;
                float4 xv = *(const float4*)(x + (size_t)row * 120 + t * 4);
                float gir = br_ + xv.x * wrv.x + xv.y * wrv.y + xv.z * wrv.z + xv.w * wrv.w;
                float giz = bz_ + xv.x * wzv.x + xv.y * wzv.y + xv.z * wzv.z + xv.w * wzv.w;
                float gin = bn_ + xv.x * wnv.x + xv.y * wnv.y + xv.z * wnv.z + xv.w * wnv.w;
                float rr = sigmoidf_(gir + acc[fi][0][j] + cr_);
                float zz = sigmoidf_(giz + acc[fi][1][j] + cz_);
                float nn = tanhf(gin + rr * (acc[fi][2][j] + cn_));
                size_t hidx = (size_t)row * 512 + u;
                float hn = (1.f - zz) * nn + zz * hf0[hidx];
                hf0[hidx] = hn;
                e0_h0out[hidx] = f2b(hn);
            }
        }
    }
}

// D: [ghd|fc] GEMM (NJ=4, K=512) + decoder cell. Fragment 3 = FC output:
// pred_{t-1} = acc[fi][3] cols 0,1 via 2 intra-wave shfls. Plain stores, no atomics.
__global__ __launch_bounds__(256)
void gemm_d(const unsigned short* __restrict__ A /* h1 ping */,
            const unsigned short* __restrict__ W,
            const float* __restrict__ dinbuf, int t,
            const float* __restrict__ Wih, const float* __restrict__ bih,
            const float* __restrict__ bhh, const float* __restrict__ bfc,
            float* __restrict__ hf, unsigned short* __restrict__ hbout,
            float* __restrict__ out)
{
    int bid = (int)blockIdx.x;
    int swz = (bid & 7) * 64 + (bid >> 3);
    const int tile_n = swz & 15;
    const int n0 = tile_n * 128;
    const int m0 = (swz >> 4) * 128;

    __shared__ unsigned short sA[2 * 128 * 64], sB[2 * 128 * 64];
    f32x4 acc[4][4];
#pragma unroll
    for (int i = 0; i < 4; ++i)
#pragma unroll
        for (int j = 0; j < 4; ++j) acc[i][j] = (f32x4){0.f, 0.f, 0.f, 0.f};

    gemm_core2<4, 512, 0>(A, A, W, m0, n0, sA, sB, acc);

    const int lane = threadIdx.x & 63;
    const int w    = threadIdx.x >> 6;
    const int wrw = w >> 1, wcw = w & 1;
    const int lr = lane & 15, q = lane >> 4;
    const int u = tile_n * 32 + wcw * 16 + lr;

    float wr0 = Wih[(size_t)u * 2],          wr1 = Wih[(size_t)u * 2 + 1];
    float wz0 = Wih[(size_t)(512 + u) * 2],  wz1 = Wih[(size_t)(512 + u) * 2 + 1];
    float wn0 = Wih[(size_t)(1024 + u) * 2], wn1 = Wih[(size_t)(1024 + u) * 2 + 1];
    float br_ = bih[u], bz_ = bih[512 + u], bn_ = bih[1024 + u];
    float cr_ = bhh[u], cz_ = bhh[512 + u], cn_ = bhh[1024 + u];
    float bfc0 = bfc[0], bfc1 = bfc[1];
    const bool wout = (tile_n == 0) && (wcw == 0) && (lr == 0);

#pragma unroll
    for (int fi = 0; fi < 4; ++fi) {
#pragma unroll
        for (int j = 0; j < 4; ++j) {
            int row = m0 + wrw * 64 + fi * 16 + q * 4 + j;
            float p0 = __shfl(acc[fi][3][j], (lane & 48) | 0) + bfc0;
            float p1 = __shfl(acc[fi][3][j], (lane & 48) | 1) + bfc1;
            float x0, x1;
            if (t == 0) { x0 = dinbuf[row * 2]; x1 = dinbuf[row * 2 + 1]; }
            else        { x0 = p0; x1 = p1; }
            float gir = br_ + x0 * wr0 + x1 * wr1;
            float giz = bz_ + x0 * wz0 + x1 * wz1;
            float gin = bn_ + x0 * wn0 + x1 * wn1;
            float rr = sigmoidf_(gir + acc[fi][0][j] + cr_);
            float zz = sigmoidf_(giz + acc[fi][1][j] + cz_);
            float nn = tanhf(gin + rr * (acc[fi][2][j] + cn_));
            size_t hidx = (size_t)row * 512 + u;
            float hn = (1.f - zz) * nn + zz * hf[hidx];
            hf[hidx] = hn;
            hbout[hidx] = f2b(hn);
            if (t > 0 && wout) {
                out[(size_t)row * 120 + (t - 1) * 2 + 0] = p0;
                out[(size_t)row * 120 + (t - 1) * 2 + 1] = p1;
            }
        }
    }
}

// Final pred_59 = Wfc @ h_60 + bfc. One 64-lane wave per batch row.
__global__ __launch_bounds__(64)
void fc_last(const unsigned short* __restrict__ hb, const float* __restrict__ Wfc,
             const float* __restrict__ bfc, float* __restrict__ out)
{
    int row = blockIdx.x, lane = threadIdx.x;
    const unsigned short* hrow = hb + (size_t)row * 512;
    float a0 = 0.f, a1 = 0.f;
#pragma unroll
    for (int kb = 0; kb < 8; ++kb) {
        int k = kb * 64 + lane;
        float hv = b2f(hrow[k]);
        a0 += hv * Wfc[k];
        a1 += hv * Wfc[512 + k];
    }
#pragma unroll
    for (int m = 32; m; m >>= 1) { a0 += __shfl_xor(a0, m); a1 += __shfl_xor(a1, m); }
    if (lane == 0) {
        out[(size_t)row * 120 + 118] = a0 + bfc[0];
        out[(size_t)row * 120 + 119] = a1 + bfc[1];
    }
}

// W0'/Wd-hh' (1536x512): row c: ublock=c/48, g=(c%48)/16, u=ublock*16+(c%16)
__global__ void wprep_rzn(const float* __restrict__ s, unsigned short* __restrict__ d)
{
    int i = blockIdx.x * 256 + threadIdx.x;   // over 1536*512
    int c = i >> 9, k = i & 511;
    int ublock = c / 48, rem = c % 48, g = rem >> 4, uoff = rem & 15;
    int u = ublock * 16 + uoff;
    d[i] = f2b(s[((size_t)(g * 512 + u)) * 512 + k]);
}

// W1'' (1536x1024): row c as above; col k: k<512 -> Wih1 gate row, k>=512 -> Whh1.
__global__ void wprep_e1(const float* __restrict__ Wih1, const float* __restrict__ Whh1,
                         unsigned short* __restrict__ d)
{
    int i = blockIdx.x * 256 + threadIdx.x;   // over 1536*1024
    int c = i >> 10, k = i & 1023;
    int ublock = c / 48, rem = c % 48, g = rem >> 4, uoff = rem & 15;
    int u = ublock * 16 + uoff;
    float v = (k < 512) ? Wih1[(size_t)(g * 512 + u) * 512 + k]
                        : Whh1[(size_t)(g * 512 + u) * 512 + (k - 512)];
    d[i] = f2b(v);
}

// Wd' (2048x512) for D: c: ublock=c>>6, g=(c>>4)&3, uoff=c&15.
// g<3: Whhd gate rows; g==3: uoff<2 -> Wfc row uoff, else 0.
__global__ void wprep_d(const float* __restrict__ Whhd, const float* __restrict__ Wfc,
                        unsigned short* __restrict__ d)
{
    int i = blockIdx.x * 256 + threadIdx.x;   // over 2048*512
    int c = i >> 9, k = i & 511;
    int ublock = c >> 6, g = (c >> 4) & 3, uoff = c & 15;
    int u = ublock * 16 + uoff;
    float v;
    if (g < 3)           v = Whhd[((size_t)(g * 512 + u)) * 512 + k];
    else if (uoff < 2)   v = Wfc[(size_t)uoff * 512 + k];
    else                 v = 0.f;
    d[i] = f2b(v);
}

__global__ void init_all(const float* __restrict__ x,
                         float* __restrict__ hf0, float* __restrict__ hf1,
                         unsigned short* __restrict__ h0a, unsigned short* __restrict__ h1a,
                         float* __restrict__ dinbuf)
{
    int idx = blockIdx.x * 256 + threadIdx.x;  // over B*512
    hf0[idx] = 0.f; hf1[idx] = 0.f;
    h0a[idx] = 0; h1a[idx] = 0;
    if (idx < B_SZ * 2)
        dinbuf[idx] = x[(size_t)(idx >> 1) * 120 + 29 * 4 + (idx & 1)];
}

extern "C" void kernel_launch(void* const* d_in, const int* in_sizes, int n_in,
                              void* d_out, int out_size, void* d_ws, size_t ws_size,
                              hipStream_t stream)
{
    const float* x    = (const float*)d_in[0];
    const float* Wih0 = (const float*)d_in[1];
    const float* Whh0 = (const float*)d_in[2];
    const float* bih0 = (const float*)d_in[3];
    const float* bhh0 = (const float*)d_in[4];
    const float* Wih1 = (const float*)d_in[5];
    const float* Whh1 = (const float*)d_in[6];
    const float* bih1 = (const float*)d_in[7];
    const float* bhh1 = (const float*)d_in[8];
    const float* Wihd = (const float*)d_in[9];
    const float* Whhd = (const float*)d_in[10];
    const float* bihd = (const float*)d_in[11];
    const float* bhhd = (const float*)d_in[12];
    const float* Wfc  = (const float*)d_in[13];
    const float* bfc  = (const float*)d_in[14];
    float* out = (float*)d_out;

    // ws: hf0,hf1 (B*512 f32) | h0[2],h1[2] (B*512 u16 each) | dinbuf | W0' | W1'' | Wd'
    char* p = (char*)d_ws;
    float* hf0 = (float*)p;  p += (size_t)B_SZ * 512 * 4;
    float* hf1 = (float*)p;  p += (size_t)B_SZ * 512 * 4;
    unsigned short* h0b_[2], *h1b_[2];
    h0b_[0] = (unsigned short*)p; p += (size_t)B_SZ * 512 * 2;
    h0b_[1] = (unsigned short*)p; p += (size_t)B_SZ * 512 * 2;
    h1b_[0] = (unsigned short*)p; p += (size_t)B_SZ * 512 * 2;
    h1b_[1] = (unsigned short*)p; p += (size_t)B_SZ * 512 * 2;
    float* dinbuf = (float*)p; p += (size_t)B_SZ * 2 * 4;
    unsigned short* W0p  = (unsigned short*)p; p += (size_t)1536 * 512 * 2;
    unsigned short* W1pp = (unsigned short*)p; p += (size_t)1536 * 1024 * 2;
    unsigned short* Wdp  = (unsigned short*)p;

    wprep_rzn<<<(1536 * 512) / 256, 256, 0, stream>>>(Whh0, W0p);
    wprep_e1<<<(1536 * 1024) / 256, 256, 0, stream>>>(Wih1, Whh1, W1pp);
    wprep_d<<<(2048 * 512) / 256, 256, 0, stream>>>(Whhd, Wfc, Wdp);
    init_all<<<(B_SZ * 512) / 256, 256, 0, stream>>>(x, hf0, hf1, h0b_[0], h1b_[0], dinbuf);

    // Encoder. h0_t in h0b_[t&1]; h1_t in h1b_[t&1].
    // E0_t: reads h0b_[t&1], writes h0b_[(t+1)&1]. E1_s: reads h0b_[(s+1)&1] + h1b_[s&1],
    // writes h1b_[(s+1)&1]. Pair P_t = {E1_{t-1}, E0_t}: E1 reads h0b_[t&1] (E0 writes the
    // other slot) -> race-free.
    // E0_0 solo:
    gemm_enc<<<512, 256, 0, stream>>>(nullptr, nullptr, nullptr, nullptr, nullptr, nullptr,
                                      nullptr,
                                      h0b_[0], h0b_[1], W0p, x, 0, Wih0, bih0, bhh0, hf0,
                                      2);
    for (int t = 1; t < TOBS; ++t) {
        int s = t - 1;
        gemm_enc<<<1024, 256, 0, stream>>>(
            h0b_[(s + 1) & 1], h1b_[s & 1], h1b_[(s + 1) & 1], W1pp, bih1, bhh1, hf1,
            h0b_[t & 1], h0b_[(t + 1) & 1], W0p, x, t, Wih0, bih0, bhh0, hf0,
            3);
    }
    // E1_29 solo:
    {
        int s = TOBS - 1;
        gemm_enc<<<512, 256, 0, stream>>>(
            h0b_[(s + 1) & 1], h1b_[s & 1], h1b_[(s + 1) & 1], W1pp, bih1, bhh1, hf1,
            nullptr, nullptr, nullptr, nullptr, 0, nullptr, nullptr, nullptr, nullptr,
            1);
    }
    // h1_30 now in h1b_[0] (TOBS=30 even). Decoder: h_dec_t in h1b_[t&1].
    for (int t = 0; t < TPRED; ++t) {
        gemm_d<<<512, 256, 0, stream>>>(h1b_[t & 1], Wdp, dinbuf, t, Wihd, bihd, bhhd, bfc,
                                        hf1, h1b_[(t + 1) & 1], out);
    }
    // pred_59 = FC(h_60); h_60 in h1b_[0] (TPRED=60 even).
    fc_last<<<B_SZ, 64, 0, stream>>>(h1b_[0], Wfc, bfc, out);
}